// Round 6
// baseline (486.457 us; speedup 1.0000x reference)
//
#include <hip/hip_runtime.h>
#include <math.h>

#define BATCH 256
#define QL 50
#define EMB 50
#define DL 2000
#define NB 11
#define SEG 8
#define RPS 250      // d rows per segment (DL/SEG)
#define TPB 256
#define HB (QL * NB) // 550

// 50-element dot: a += q_e * d_e, e ascending 0..49 (bitwise-identical chain;
// fmaf(q,d,a) == fmaf(d,q,a)). d from wave-uniform scalar loads.
#define DOT50 \
  a = fmaf(q0.x,  drow[ 0], a); a = fmaf(q0.y,  drow[ 1], a); \
  a = fmaf(q0.z,  drow[ 2], a); a = fmaf(q0.w,  drow[ 3], a); \
  a = fmaf(q1.x,  drow[ 4], a); a = fmaf(q1.y,  drow[ 5], a); \
  a = fmaf(q1.z,  drow[ 6], a); a = fmaf(q1.w,  drow[ 7], a); \
  a = fmaf(q2.x,  drow[ 8], a); a = fmaf(q2.y,  drow[ 9], a); \
  a = fmaf(q2.z,  drow[10], a); a = fmaf(q2.w,  drow[11], a); \
  a = fmaf(q3.x,  drow[12], a); a = fmaf(q3.y,  drow[13], a); \
  a = fmaf(q3.z,  drow[14], a); a = fmaf(q3.w,  drow[15], a); \
  a = fmaf(q4.x,  drow[16], a); a = fmaf(q4.y,  drow[17], a); \
  a = fmaf(q4.z,  drow[18], a); a = fmaf(q4.w,  drow[19], a); \
  a = fmaf(q5.x,  drow[20], a); a = fmaf(q5.y,  drow[21], a); \
  a = fmaf(q5.z,  drow[22], a); a = fmaf(q5.w,  drow[23], a); \
  a = fmaf(q6.x,  drow[24], a); a = fmaf(q6.y,  drow[25], a); \
  a = fmaf(q6.z,  drow[26], a); a = fmaf(q6.w,  drow[27], a); \
  a = fmaf(q7.x,  drow[28], a); a = fmaf(q7.y,  drow[29], a); \
  a = fmaf(q7.z,  drow[30], a); a = fmaf(q7.w,  drow[31], a); \
  a = fmaf(q8.x,  drow[32], a); a = fmaf(q8.y,  drow[33], a); \
  a = fmaf(q8.z,  drow[34], a); a = fmaf(q8.w,  drow[35], a); \
  a = fmaf(q9.x,  drow[36], a); a = fmaf(q9.y,  drow[37], a); \
  a = fmaf(q9.z,  drow[38], a); a = fmaf(q9.w,  drow[39], a); \
  a = fmaf(q10.x, drow[40], a); a = fmaf(q10.y, drow[41], a); \
  a = fmaf(q10.z, drow[42], a); a = fmaf(q10.w, drow[43], a); \
  a = fmaf(q11.x, drow[44], a); a = fmaf(q11.y, drow[45], a); \
  a = fmaf(q11.z, drow[46], a); a = fmaf(q11.w, drow[47], a); \
  a = fmaf(qc.x,  drow[48], a); a = fmaf(qc.y,  drow[49], a);

// q self-norm, same values, e ascending (bitwise-identical to prior qrn chain)
#define QSS50 \
  qss = fmaf(q0.x,q0.x,qss);   qss = fmaf(q0.y,q0.y,qss); \
  qss = fmaf(q0.z,q0.z,qss);   qss = fmaf(q0.w,q0.w,qss); \
  qss = fmaf(q1.x,q1.x,qss);   qss = fmaf(q1.y,q1.y,qss); \
  qss = fmaf(q1.z,q1.z,qss);   qss = fmaf(q1.w,q1.w,qss); \
  qss = fmaf(q2.x,q2.x,qss);   qss = fmaf(q2.y,q2.y,qss); \
  qss = fmaf(q2.z,q2.z,qss);   qss = fmaf(q2.w,q2.w,qss); \
  qss = fmaf(q3.x,q3.x,qss);   qss = fmaf(q3.y,q3.y,qss); \
  qss = fmaf(q3.z,q3.z,qss);   qss = fmaf(q3.w,q3.w,qss); \
  qss = fmaf(q4.x,q4.x,qss);   qss = fmaf(q4.y,q4.y,qss); \
  qss = fmaf(q4.z,q4.z,qss);   qss = fmaf(q4.w,q4.w,qss); \
  qss = fmaf(q5.x,q5.x,qss);   qss = fmaf(q5.y,q5.y,qss); \
  qss = fmaf(q5.z,q5.z,qss);   qss = fmaf(q5.w,q5.w,qss); \
  qss = fmaf(q6.x,q6.x,qss);   qss = fmaf(q6.y,q6.y,qss); \
  qss = fmaf(q6.z,q6.z,qss);   qss = fmaf(q6.w,q6.w,qss); \
  qss = fmaf(q7.x,q7.x,qss);   qss = fmaf(q7.y,q7.y,qss); \
  qss = fmaf(q7.z,q7.z,qss);   qss = fmaf(q7.w,q7.w,qss); \
  qss = fmaf(q8.x,q8.x,qss);   qss = fmaf(q8.y,q8.y,qss); \
  qss = fmaf(q8.z,q8.z,qss);   qss = fmaf(q8.w,q8.w,qss); \
  qss = fmaf(q9.x,q9.x,qss);   qss = fmaf(q9.y,q9.y,qss); \
  qss = fmaf(q9.z,q9.z,qss);   qss = fmaf(q9.w,q9.w,qss); \
  qss = fmaf(q10.x,q10.x,qss); qss = fmaf(q10.y,q10.y,qss); \
  qss = fmaf(q10.z,q10.z,qss); qss = fmaf(q10.w,q10.w,qss); \
  qss = fmaf(q11.x,q11.x,qss); qss = fmaf(q11.y,q11.y,qss); \
  qss = fmaf(q11.z,q11.z,qss); qss = fmaf(q11.w,q11.w,qss); \
  qss = fmaf(qc.x,qc.x,qss);   qss = fmaf(qc.y,qc.y,qss);

// ------------- main kernel: q per lane (regs), d wave-uniform (SGPR) -------------
__global__ __launch_bounds__(TPB, 4)
void sim_hist_kernel(const float* __restrict__ de,
                     const int*   __restrict__ did,
                     const float* __restrict__ qe,
                     const int*   __restrict__ qid,
                     const float* __restrict__ Wg,
                     unsigned short* __restrict__ g_hist,  // [B][SEG][HB]
                     float* __restrict__ gate)
{
    const int bid  = blockIdx.x;
    const int b    = bid >> 3;
    const int seg  = bid & 7;
    const int t    = threadIdx.x;
    const int lane = t & 63;
    const int wid  = t >> 6;

    __shared__ float    s_drn[RPS];
    __shared__ int      s_dval[RPS];
    __shared__ unsigned s_hist[HB];
    __shared__ float    r2s[4];

    for (int i = t; i < HB; i += TPB) s_hist[i] = 0u;

    // ---- phase 1: d-row norms + validity (one thread per row, exact chain) ----
    if (t < RPS) {
        const int rowg = seg * RPS + t;
        const float* src = de + ((size_t)b * DL + rowg) * EMB;
        float ss = 0.f;
        #pragma unroll
        for (int ep = 0; ep < 25; ++ep) {
            const float2 v = *(const float2*)(src + 2 * ep);
            ss = fmaf(v.x, v.x, ss);
            ss = fmaf(v.y, v.y, ss);
        }
        s_drn[t]  = 1.0f / (sqrtf(ss) + 1e-8f);
        s_dval[t] = (did[(size_t)b * DL + rowg] > 0) ? 1 : 0;
    }

    // ---- q row of THIS lane into named registers (lanes >= 50 clamp to q0, masked) ----
    const int ql = (lane < QL) ? lane : 0;
    const float* qrow = qe + ((size_t)b * QL + ql) * EMB;
    const float4 q0  = *(const float4*)(qrow +  0);
    const float4 q1  = *(const float4*)(qrow +  4);
    const float4 q2  = *(const float4*)(qrow +  8);
    const float4 q3  = *(const float4*)(qrow + 12);
    const float4 q4  = *(const float4*)(qrow + 16);
    const float4 q5  = *(const float4*)(qrow + 20);
    const float4 q6  = *(const float4*)(qrow + 24);
    const float4 q7  = *(const float4*)(qrow + 28);
    const float4 q8  = *(const float4*)(qrow + 32);
    const float4 q9  = *(const float4*)(qrow + 36);
    const float4 q10 = *(const float4*)(qrow + 40);
    const float4 q11 = *(const float4*)(qrow + 44);
    const float2 qc  = *(const float2*)(qrow + 48);

    float qss = 0.f;
    QSS50
    const float qrn = 1.0f / (sqrtf(qss) + 1e-8f);
    const bool  qok = (lane < QL) && (qid[(size_t)b * QL + ql] > 0);

    __syncthreads();

    // ---- phase 2: each wave walks d rows; row data via wave-uniform scalar loads ----
    const float* dbase = de + (size_t)b * DL * EMB;
    #pragma unroll 1
    for (int r = wid; r < RPS; r += 4) {
        const int ru = __builtin_amdgcn_readfirstlane(r);   // force SGPR-uniform
        if (!s_dval[ru]) continue;                          // invalid d row: no counts
        const float* drow = dbase + (size_t)(seg * RPS + ru) * EMB;  // uniform -> s_load
        const float  drn  = s_drn[ru];                      // LDS broadcast
        float a = 0.f;
        DOT50
        const float s_ = a * qrn * drn;                     // (a*qrn)*drn, exact order
        const float tt = ((s_ + 1.000001f) * 0.5f) * 10.0f;
        int bb = (int)tt;
        bb = bb < 0 ? 0 : (bb > 10 ? 10 : bb);
        if (qok) atomicAdd(&s_hist[ql * NB + bb], 1u);      // unique addr per lane
    }

    __syncthreads();

    // ---- flush: plain u16 stores to this block's private segment histogram ----
    for (int i = t; i < HB; i += TPB)
        g_hist[((size_t)b * SEG + seg) * HB + i] = (unsigned short)s_hist[i];

    // ---- gate dot for this batch (seg==0 blocks only; verbatim exact code) ----
    if (seg == 0) {
        const float* qb = qe + (size_t)b * QL * EMB;
        float a2 = 0.f;
        for (int i = t; i < QL * EMB; i += TPB)
            a2 = fmaf(qb[i], Wg[i], a2);
        #pragma unroll
        for (int off = 32; off > 0; off >>= 1) a2 += __shfl_down(a2, off, 64);
        if ((t & 63) == 0) r2s[t >> 6] = a2;
        __syncthreads();
        if (t == 0) gate[b] = r2s[0] + r2s[1] + r2s[2] + r2s[3];
    }
}

// ------------- ffn: integer-sum 8 segment hists, then exact log/fmaf/tree -------------
__global__ __launch_bounds__(TPB)
void ffn_kernel(const unsigned short* __restrict__ g_hist,
                const float* __restrict__ W1,
                const float* __restrict__ bias,
                float* __restrict__ ffn)
{
    const int b = blockIdx.x;
    const int t = threadIdx.x;
    const unsigned short* hb = g_hist + (size_t)b * SEG * HB;

    float a1 = 0.f;
    for (int i = t; i < HB; i += TPB) {
        unsigned c = 0;
        #pragma unroll
        for (int s = 0; s < SEG; ++s) c += hb[s * HB + i];  // integer: exact any order
        a1 = fmaf(logf((float)c + 1e-5f), W1[i], a1);
    }

    #pragma unroll
    for (int off = 32; off > 0; off >>= 1) a1 += __shfl_down(a1, off, 64);
    __shared__ float r1s[4];
    if ((t & 63) == 0) r1s[t >> 6] = a1;
    __syncthreads();
    if (t == 0) ffn[b] = r1s[0] + r1s[1] + r1s[2] + r1s[3] + bias[0];
}

// ------------- softmax over batch + final score (verbatim, passed) -------------
__global__ __launch_bounds__(TPB)
void score_kernel(const float* __restrict__ ffn,
                  const float* __restrict__ gate,
                  float* __restrict__ out)
{
    const int t = threadIdx.x;  // one block of 256 == BATCH
    __shared__ float buf[4];
    __shared__ float sM, sZ, sS;

    const float g = gate[t];

    float m = g;
    #pragma unroll
    for (int off = 32; off > 0; off >>= 1) m = fmaxf(m, __shfl_down(m, off, 64));
    if ((t & 63) == 0) buf[t >> 6] = m;
    __syncthreads();
    if (t == 0) sM = fmaxf(fmaxf(buf[0], buf[1]), fmaxf(buf[2], buf[3]));
    __syncthreads();

    const float e = expf(g - sM);
    float z = e;
    #pragma unroll
    for (int off = 32; off > 0; off >>= 1) z += __shfl_down(z, off, 64);
    __syncthreads();
    if ((t & 63) == 0) buf[t >> 6] = z;
    __syncthreads();
    if (t == 0) sZ = buf[0] + buf[1] + buf[2] + buf[3];
    __syncthreads();

    float p = e / sZ;
    float s = p;
    #pragma unroll
    for (int off = 32; off > 0; off >>= 1) s += __shfl_down(s, off, 64);
    __syncthreads();
    if ((t & 63) == 0) buf[t >> 6] = s;
    __syncthreads();
    if (t == 0) sS = buf[0] + buf[1] + buf[2] + buf[3];
    __syncthreads();

    out[t] = ffn[t] * sS;
}

// ---------------- launcher: 3 dispatches, no memset ----------------
extern "C" void kernel_launch(void* const* d_in, const int* in_sizes, int n_in,
                              void* d_out, int out_size, void* d_ws, size_t ws_size,
                              hipStream_t stream)
{
    const float* qe  = (const float*)d_in[0];
    const float* de  = (const float*)d_in[1];
    const float* W1  = (const float*)d_in[2];
    const float* b1  = (const float*)d_in[3];
    const float* Wg  = (const float*)d_in[4];
    const int*   qid = (const int*)d_in[5];
    const int*   did = (const int*)d_in[6];
    float* out = (float*)d_out;

    // workspace layout (~2.26 MB, under the 3.64 MB proven budget)
    char* ws = (char*)d_ws;
    unsigned short* g_hist = (unsigned short*)ws;            // 2,252,800 B
    float* ffn  = (float*)(ws + 2252800);                    //     1,024 B
    float* gate = ffn + BATCH;                               //     1,024 B

    sim_hist_kernel<<<BATCH * SEG, TPB, 0, stream>>>(de, did, qe, qid, Wg, g_hist, gate);
    ffn_kernel<<<BATCH, TPB, 0, stream>>>(g_hist, W1, b1, ffn);
    score_kernel<<<1, TPB, 0, stream>>>(ffn, gate, out);
}

// Round 8
// 234.349 us; speedup vs baseline: 2.0758x; 2.0758x over previous
//
#include <hip/hip_runtime.h>
#include <math.h>

#define BATCH 256
#define QL 50
#define EMB 50
#define DL 2000
#define NB 11
#define SEG 16
#define RPB 125      // d rows per block (DL/SEG)
#define TPB 256
#define NKP 25       // e-pairs
#define HB (QL * NB) // 550

// ---- 5x5 register tile macros ----
#define FOR_M5(M) M(0) M(1) M(2) M(3) M(4)
#define FOR_MN(M) \
  M(0,0) M(0,1) M(0,2) M(0,3) M(0,4) \
  M(1,0) M(1,1) M(1,2) M(1,3) M(1,4) \
  M(2,0) M(2,1) M(2,2) M(2,3) M(2,4) \
  M(3,0) M(3,1) M(3,2) M(3,3) M(3,4) \
  M(4,0) M(4,1) M(4,2) M(4,3) M(4,4)

#define DECL_ACC(m,n) float a_##m##_##n = 0.f;
#define LOAD_Q(m) const float2 qv##m = s_q2[kq + qg5 + m];
#define LOAD_D(n) const float2 dv##n = s_d2[kd + rg5 + n];
// e-ascending exact chain per accumulator (2*kp then 2*kp+1)
#define FMA2(m,n) a_##m##_##n = fmaf(qv##m.x, dv##n.x, a_##m##_##n); \
                  a_##m##_##n = fmaf(qv##m.y, dv##n.y, a_##m##_##n);
// binning verbatim from all passing rounds: ((a*qrn)*drn), trunc, clamp
#define HIST_MN(m,n) if (qv_##m && dv_##n) { \
    const float s_  = a_##m##_##n * qrn##m * drn##n; \
    const float tt_ = ((s_ + 1.000001f) * 0.5f) * 10.0f; \
    int bb_ = (int)tt_; bb_ = bb_ < 0 ? 0 : (bb_ > 10 ? 10 : bb_); \
    atomicAdd(&s_hist[(qg5 + m) * NB + bb_], 1u); }

// ---------------- sim+hist (+gate on seg==0) ----------------
__global__ __launch_bounds__(TPB)
void sim_hist_kernel(const float* __restrict__ de,
                     const int*   __restrict__ did,
                     const float* __restrict__ qe,
                     const int*   __restrict__ qid,
                     const float* __restrict__ Wg,
                     unsigned char* __restrict__ g_hist, // [B][SEG][HB]
                     float* __restrict__ gate,
                     int* __restrict__ cnt)
{
    const int bid = blockIdx.x;
    const int b   = bid >> 4;
    const int seg = bid & 15;
    const int t   = threadIdx.x;

    __shared__ float2   s_d2[NKP * RPB];   // 25,000 B  [ep][r]
    __shared__ float2   s_q2[NKP * QL];    // 10,000 B  [ep][q]
    __shared__ float    s_qrn[QL];
    __shared__ float    s_drn[RPB];
    __shared__ int      s_qv[QL];
    __shared__ int      s_dval[RPB];
    __shared__ unsigned s_hist[HB];
    __shared__ float    r2s[4];

    if (bid == 0 && t == 0) *cnt = 0;      // re-arm epilogue flag each launch
    for (int i = t; i < HB; i += TPB) s_hist[i] = 0u;

    // ---- stage d-tile and q-block into LDS (contiguous global reads) ----
    const float* dbase = de + ((size_t)b * DL + seg * RPB) * EMB;
    for (int i = t; i < NKP * RPB; i += TPB) {
        const int r  = i / NKP;
        const int ep = i - r * NKP;
        s_d2[ep * RPB + r] = *(const float2*)(dbase + r * EMB + 2 * ep);
    }
    const float* qbase = qe + (size_t)b * QL * EMB;
    for (int i = t; i < NKP * QL; i += TPB) {
        const int q  = i / NKP;
        const int ep = i - q * NKP;
        s_q2[ep * QL + q] = *(const float2*)(qbase + q * EMB + 2 * ep);
    }
    __syncthreads();

    // ---- norms from LDS (identical bits), exact e-ascending fmaf chains ----
    if (t < RPB) {
        float ss = 0.f;
        #pragma unroll
        for (int ep = 0; ep < NKP; ++ep) {
            const float2 v = s_d2[ep * RPB + t];
            ss = fmaf(v.x, v.x, ss);
            ss = fmaf(v.y, v.y, ss);
        }
        s_drn[t]  = 1.0f / (sqrtf(ss) + 1e-8f);
        s_dval[t] = (did[(size_t)b * DL + seg * RPB + t] > 0) ? 1 : 0;
    }
    if (t < QL) {
        float ss = 0.f;
        #pragma unroll
        for (int ep = 0; ep < NKP; ++ep) {
            const float2 v = s_q2[ep * QL + t];
            ss = fmaf(v.x, v.x, ss);
            ss = fmaf(v.y, v.y, ss);
        }
        s_qrn[t] = 1.0f / (sqrtf(ss) + 1e-8f);
        s_qv[t]  = (qid[(size_t)b * QL + t] > 0) ? 1 : 0;
    }
    __syncthreads();

    // ---- 5x5 register-tiled dot products ----
    if (t < 250) {
        const int qg5 = (t % 10) * 5;      // adjacent lanes -> different q group
        const int rg5 = (t / 10) * 5;
        FOR_MN(DECL_ACC)
        #pragma unroll 1
        for (int kp = 0; kp < NKP; ++kp) { // rolled: live set stays ~60 VGPR
            const int kq = kp * QL;
            const int kd = kp * RPB;
            FOR_M5(LOAD_Q)
            FOR_M5(LOAD_D)
            FOR_MN(FMA2)                   // 50 fmacs per 10 LDS reads
        }
        const float qrn0 = s_qrn[qg5+0], qrn1 = s_qrn[qg5+1], qrn2 = s_qrn[qg5+2],
                    qrn3 = s_qrn[qg5+3], qrn4 = s_qrn[qg5+4];
        const float drn0 = s_drn[rg5+0], drn1 = s_drn[rg5+1], drn2 = s_drn[rg5+2],
                    drn3 = s_drn[rg5+3], drn4 = s_drn[rg5+4];
        const int qv_0 = s_qv[qg5+0], qv_1 = s_qv[qg5+1], qv_2 = s_qv[qg5+2],
                  qv_3 = s_qv[qg5+3], qv_4 = s_qv[qg5+4];
        const int dv_0 = s_dval[rg5+0], dv_1 = s_dval[rg5+1], dv_2 = s_dval[rg5+2],
                  dv_3 = s_dval[rg5+3], dv_4 = s_dval[rg5+4];
        FOR_MN(HIST_MN)                    // 25 LDS atomics, lane-staggered q
    }
    __syncthreads();

    // ---- flush block-private u8 histogram (max count 125 < 256) ----
    unsigned char* hout = g_hist + ((size_t)b * SEG + seg) * HB;
    for (int i = t; i < HB; i += TPB) hout[i] = (unsigned char)s_hist[i];

    // ---- gate dot (seg==0 only; verbatim exact code, passed R6) ----
    if (seg == 0) {
        float a2 = 0.f;
        for (int i = t; i < QL * EMB; i += TPB)
            a2 = fmaf(qbase[i], Wg[i], a2);
        #pragma unroll
        for (int off = 32; off > 0; off >>= 1) a2 += __shfl_down(a2, off, 64);
        if ((t & 63) == 0) r2s[t >> 6] = a2;
        __syncthreads();
        if (t == 0) gate[b] = r2s[0] + r2s[1] + r2s[2] + r2s[3];
    }
}

// ---------------- ffn + (last block) softmax/score ----------------
__global__ __launch_bounds__(TPB)
void ffn_score_kernel(const unsigned char* __restrict__ g_hist,
                      const float* __restrict__ W1,
                      const float* __restrict__ bias,
                      const float* __restrict__ gate,
                      float* __restrict__ ffn,
                      int* __restrict__ cnt,
                      float* __restrict__ out)
{
    const int b = blockIdx.x;
    const int t = threadIdx.x;
    const unsigned char* hb = g_hist + (size_t)b * SEG * HB;

    float a1 = 0.f;
    for (int i = t; i < HB; i += TPB) {
        unsigned c = 0;
        #pragma unroll
        for (int s = 0; s < SEG; ++s) c += hb[s * HB + i];  // integer: exact
        a1 = fmaf(logf((float)c + 1e-5f), W1[i], a1);
    }
    #pragma unroll
    for (int off = 32; off > 0; off >>= 1) a1 += __shfl_down(a1, off, 64);
    __shared__ float r1s[4];
    __shared__ int   s_last;
    if ((t & 63) == 0) r1s[t >> 6] = a1;
    __syncthreads();
    if (t == 0) {
        const float v = r1s[0] + r1s[1] + r1s[2] + r1s[3] + bias[0];
        atomicExch(&ffn[b], v);            // device-coherent publish
        __threadfence();
        const int old = atomicAdd(cnt, 1);
        s_last = (old == BATCH - 1) ? 1 : 0;
    }
    __syncthreads();
    if (!s_last) return;
    __threadfence();

    // ---- score: verbatim exact softmax-over-batch path ----
    __shared__ float buf[4];
    __shared__ float sM, sZ, sS;
    const float g = gate[t];                       // produced by prior dispatch
    const float f = atomicAdd(&ffn[t], 0.0f);      // device-coherent read

    float m = g;
    #pragma unroll
    for (int off = 32; off > 0; off >>= 1) m = fmaxf(m, __shfl_down(m, off, 64));
    if ((t & 63) == 0) buf[t >> 6] = m;
    __syncthreads();
    if (t == 0) sM = fmaxf(fmaxf(buf[0], buf[1]), fmaxf(buf[2], buf[3]));
    __syncthreads();

    const float e = expf(g - sM);
    float z = e;
    #pragma unroll
    for (int off = 32; off > 0; off >>= 1) z += __shfl_down(z, off, 64);
    __syncthreads();
    if ((t & 63) == 0) buf[t >> 6] = z;
    __syncthreads();
    if (t == 0) sZ = buf[0] + buf[1] + buf[2] + buf[3];
    __syncthreads();

    const float p = e / sZ;
    float s = p;
    #pragma unroll
    for (int off = 32; off > 0; off >>= 1) s += __shfl_down(s, off, 64);
    __syncthreads();
    if ((t & 63) == 0) buf[t >> 6] = s;
    __syncthreads();
    if (t == 0) sS = buf[0] + buf[1] + buf[2] + buf[3];
    __syncthreads();

    out[t] = f * sS;
}

// ---------------- launcher: 2 dispatches ----------------
extern "C" void kernel_launch(void* const* d_in, const int* in_sizes, int n_in,
                              void* d_out, int out_size, void* d_ws, size_t ws_size,
                              hipStream_t stream)
{
    const float* qe  = (const float*)d_in[0];
    const float* de  = (const float*)d_in[1];
    const float* W1  = (const float*)d_in[2];
    const float* b1  = (const float*)d_in[3];
    const float* Wg  = (const float*)d_in[4];
    const int*   qid = (const int*)d_in[5];
    const int*   did = (const int*)d_in[6];
    float* out = (float*)d_out;

    // workspace (~2.26 MB)
    char* ws = (char*)d_ws;
    unsigned char* g_hist = (unsigned char*)ws;        // 256*16*550 = 2,252,800 B
    float* gate = (float*)(ws + 2252800);              // 1,024 B
    float* ffn  = gate + BATCH;                        // 1,024 B
    int*   cnt  = (int*)(ffn + BATCH);                 // 4 B

    sim_hist_kernel<<<BATCH * SEG, TPB, 0, stream>>>(de, did, qe, qid, Wg,
                                                     g_hist, gate, cnt);
    ffn_score_kernel<<<BATCH, TPB, 0, stream>>>(g_hist, W1, b1, gate, ffn, cnt, out);
}

// Round 9
// 193.956 us; speedup vs baseline: 2.5081x; 1.2083x over previous
//
#include <hip/hip_runtime.h>
#include <math.h>

#define BATCH 256
#define QL 50
#define EMB 50
#define DL 2000
#define NB 11
#define SEG 16
#define RPB 125      // d rows per block (DL/SEG)
#define TPB 256
#define RSTRIDE 52   // LDS row stride in floats: 208 B = 13*16 -> float4-aligned rows
#define HB (QL * NB) // 550

// ---- 5x5 register tile macros ----
#define FOR_M5(M) M(0) M(1) M(2) M(3) M(4)
#define FOR_MN(M) \
  M(0,0) M(0,1) M(0,2) M(0,3) M(0,4) \
  M(1,0) M(1,1) M(1,2) M(1,3) M(1,4) \
  M(2,0) M(2,1) M(2,2) M(2,3) M(2,4) \
  M(3,0) M(3,1) M(3,2) M(3,3) M(3,4) \
  M(4,0) M(4,1) M(4,2) M(4,3) M(4,4)

#define DECL_ACC(m,n) float a_##m##_##n = 0.f;
#define LOAD_Q4(m) const float4 qv##m = *(const float4*)(qb0 + (m) * RSTRIDE + 4 * k);
#define LOAD_D4(n) const float4 dv##n = *(const float4*)(db0 + (n) * RSTRIDE + 4 * k);
#define LOAD_Q2(m) const float2 qt##m = *(const float2*)(qb0 + (m) * RSTRIDE + 48);
#define LOAD_D2(n) const float2 dt##n = *(const float2*)(db0 + (n) * RSTRIDE + 48);
// e-ascending exact chain: quads k=0..11 cover e=0..47, then tail e=48,49
#define FMA4(m,n) \
  a_##m##_##n = fmaf(qv##m.x, dv##n.x, a_##m##_##n); \
  a_##m##_##n = fmaf(qv##m.y, dv##n.y, a_##m##_##n); \
  a_##m##_##n = fmaf(qv##m.z, dv##n.z, a_##m##_##n); \
  a_##m##_##n = fmaf(qv##m.w, dv##n.w, a_##m##_##n);
#define FMA2T(m,n) \
  a_##m##_##n = fmaf(qt##m.x, dt##n.x, a_##m##_##n); \
  a_##m##_##n = fmaf(qt##m.y, dt##n.y, a_##m##_##n);
// binning verbatim from all passing rounds: ((a*qrn)*drn), trunc, clamp
#define HIST_MN(m,n) if (qv_##m && dv_##n) { \
    const float s_  = a_##m##_##n * qrn##m * drn##n; \
    const float tt_ = ((s_ + 1.000001f) * 0.5f) * 10.0f; \
    int bb_ = (int)tt_; bb_ = bb_ < 0 ? 0 : (bb_ > 10 ? 10 : bb_); \
    atomicAdd(&s_hist[(qg5 + m) * NB + bb_], 1u); }

// ---------------- sim+hist (+gate on seg==0) ----------------
__global__ __launch_bounds__(TPB, 4)
void sim_hist_kernel(const float* __restrict__ de,
                     const int*   __restrict__ did,
                     const float* __restrict__ qe,
                     const int*   __restrict__ qid,
                     const float* __restrict__ Wg,
                     unsigned char* __restrict__ g_hist, // [B][SEG][HB]
                     float* __restrict__ gate,
                     int* __restrict__ cnt)
{
    const int bid = blockIdx.x;
    const int b   = bid >> 4;
    const int seg = bid & 15;
    const int t   = threadIdx.x;

    __shared__ __align__(16) float s_d[RPB * RSTRIDE]; // 26,000 B row-major
    __shared__ __align__(16) float s_q[QL * RSTRIDE];  // 10,400 B row-major
    __shared__ float         s_drn[RPB];
    __shared__ float         s_qrn[QL];
    __shared__ unsigned char s_dval[RPB];
    __shared__ unsigned char s_qv[QL];
    __shared__ unsigned      s_hist[HB];
    __shared__ float         r2s[4];

    if (bid == 0 && t == 0) *cnt = 0;      // re-arm epilogue flag each launch
    for (int i = t; i < HB; i += TPB) s_hist[i] = 0u;

    // ---- fused stage + norm, one phase one barrier ----
    // threads 0..124: d row t (copy float2 + exact e-ascending norm chain)
    // threads 128..177: q row t-128 (same pattern)
    if (t < RPB) {
        const float* src = de + ((size_t)b * DL + seg * RPB + t) * EMB;
        float* dst = s_d + t * RSTRIDE;
        float ss = 0.f;
        #pragma unroll
        for (int ep = 0; ep < 25; ++ep) {
            const float2 v = *(const float2*)(src + 2 * ep);
            ss = fmaf(v.x, v.x, ss);
            ss = fmaf(v.y, v.y, ss);
            *(float2*)(dst + 2 * ep) = v;
        }
        s_drn[t]  = 1.0f / (sqrtf(ss) + 1e-8f);
        s_dval[t] = (did[(size_t)b * DL + seg * RPB + t] > 0) ? 1 : 0;
    } else if (t >= 128 && t < 128 + QL) {
        const int j = t - 128;
        const float* src = qe + ((size_t)b * QL + j) * EMB;
        float* dst = s_q + j * RSTRIDE;
        float ss = 0.f;
        #pragma unroll
        for (int ep = 0; ep < 25; ++ep) {
            const float2 v = *(const float2*)(src + 2 * ep);
            ss = fmaf(v.x, v.x, ss);
            ss = fmaf(v.y, v.y, ss);
            *(float2*)(dst + 2 * ep) = v;
        }
        s_qrn[j] = 1.0f / (sqrtf(ss) + 1e-8f);
        s_qv[j]  = (qid[(size_t)b * QL + j] > 0) ? 1 : 0;
    }
    __syncthreads();

    // ---- 5x5 register-tiled dot products, b128 LDS reads ----
    if (t < 250) {
        const int qg5 = (t % 10) * 5;      // adjacent lanes -> different q group
        const int rg5 = (t / 10) * 5;
        const float* qb0 = s_q + qg5 * RSTRIDE;
        const float* db0 = s_d + rg5 * RSTRIDE;
        FOR_MN(DECL_ACC)
        #pragma unroll 1
        for (int k = 0; k < 12; ++k) {     // rolled: live set ~75 VGPR, no hoist
            FOR_M5(LOAD_Q4)
            FOR_M5(LOAD_D4)
            FOR_MN(FMA4)                   // 100 fmacs per 10 ds_read_b128
        }
        {                                  // tail e = 48,49
            FOR_M5(LOAD_Q2)
            FOR_M5(LOAD_D2)
            FOR_MN(FMA2T)
        }
        const float qrn0 = s_qrn[qg5+0], qrn1 = s_qrn[qg5+1], qrn2 = s_qrn[qg5+2],
                    qrn3 = s_qrn[qg5+3], qrn4 = s_qrn[qg5+4];
        const float drn0 = s_drn[rg5+0], drn1 = s_drn[rg5+1], drn2 = s_drn[rg5+2],
                    drn3 = s_drn[rg5+3], drn4 = s_drn[rg5+4];
        const int qv_0 = s_qv[qg5+0], qv_1 = s_qv[qg5+1], qv_2 = s_qv[qg5+2],
                  qv_3 = s_qv[qg5+3], qv_4 = s_qv[qg5+4];
        const int dv_0 = s_dval[rg5+0], dv_1 = s_dval[rg5+1], dv_2 = s_dval[rg5+2],
                  dv_3 = s_dval[rg5+3], dv_4 = s_dval[rg5+4];
        FOR_MN(HIST_MN)                    // 25 LDS atomics, lane-staggered q
    }
    __syncthreads();

    // ---- flush block-private u8 histogram (max count 125 < 256) ----
    unsigned char* hout = g_hist + ((size_t)b * SEG + seg) * HB;
    for (int i = t; i < HB; i += TPB) hout[i] = (unsigned char)s_hist[i];

    // ---- gate dot (seg==0 only; verbatim exact code, passed R6/R8) ----
    if (seg == 0) {
        const float* qbase = qe + (size_t)b * QL * EMB;
        float a2 = 0.f;
        for (int i = t; i < QL * EMB; i += TPB)
            a2 = fmaf(qbase[i], Wg[i], a2);
        #pragma unroll
        for (int off = 32; off > 0; off >>= 1) a2 += __shfl_down(a2, off, 64);
        if ((t & 63) == 0) r2s[t >> 6] = a2;
        __syncthreads();
        if (t == 0) gate[b] = r2s[0] + r2s[1] + r2s[2] + r2s[3];
    }
}

// ---------------- ffn + (last block) softmax/score (verbatim, passed R8) ----------------
__global__ __launch_bounds__(TPB)
void ffn_score_kernel(const unsigned char* __restrict__ g_hist,
                      const float* __restrict__ W1,
                      const float* __restrict__ bias,
                      const float* __restrict__ gate,
                      float* __restrict__ ffn,
                      int* __restrict__ cnt,
                      float* __restrict__ out)
{
    const int b = blockIdx.x;
    const int t = threadIdx.x;
    const unsigned char* hb = g_hist + (size_t)b * SEG * HB;

    float a1 = 0.f;
    for (int i = t; i < HB; i += TPB) {
        unsigned c = 0;
        #pragma unroll
        for (int s = 0; s < SEG; ++s) c += hb[s * HB + i];  // integer: exact
        a1 = fmaf(logf((float)c + 1e-5f), W1[i], a1);
    }
    #pragma unroll
    for (int off = 32; off > 0; off >>= 1) a1 += __shfl_down(a1, off, 64);
    __shared__ float r1s[4];
    __shared__ int   s_last;
    if ((t & 63) == 0) r1s[t >> 6] = a1;
    __syncthreads();
    if (t == 0) {
        const float v = r1s[0] + r1s[1] + r1s[2] + r1s[3] + bias[0];
        atomicExch(&ffn[b], v);            // device-coherent publish
        __threadfence();
        const int old = atomicAdd(cnt, 1);
        s_last = (old == BATCH - 1) ? 1 : 0;
    }
    __syncthreads();
    if (!s_last) return;
    __threadfence();

    // ---- score: verbatim exact softmax-over-batch path ----
    __shared__ float buf[4];
    __shared__ float sM, sZ, sS;
    const float g = gate[t];
    const float f = atomicAdd(&ffn[t], 0.0f);      // device-coherent read

    float m = g;
    #pragma unroll
    for (int off = 32; off > 0; off >>= 1) m = fmaxf(m, __shfl_down(m, off, 64));
    if ((t & 63) == 0) buf[t >> 6] = m;
    __syncthreads();
    if (t == 0) sM = fmaxf(fmaxf(buf[0], buf[1]), fmaxf(buf[2], buf[3]));
    __syncthreads();

    const float e = expf(g - sM);
    float z = e;
    #pragma unroll
    for (int off = 32; off > 0; off >>= 1) z += __shfl_down(z, off, 64);
    __syncthreads();
    if ((t & 63) == 0) buf[t >> 6] = z;
    __syncthreads();
    if (t == 0) sZ = buf[0] + buf[1] + buf[2] + buf[3];
    __syncthreads();

    const float p = e / sZ;
    float s = p;
    #pragma unroll
    for (int off = 32; off > 0; off >>= 1) s += __shfl_down(s, off, 64);
    __syncthreads();
    if ((t & 63) == 0) buf[t >> 6] = s;
    __syncthreads();
    if (t == 0) sS = buf[0] + buf[1] + buf[2] + buf[3];
    __syncthreads();

    out[t] = f * sS;
}

// ---------------- launcher: 2 dispatches ----------------
extern "C" void kernel_launch(void* const* d_in, const int* in_sizes, int n_in,
                              void* d_out, int out_size, void* d_ws, size_t ws_size,
                              hipStream_t stream)
{
    const float* qe  = (const float*)d_in[0];
    const float* de  = (const float*)d_in[1];
    const float* W1  = (const float*)d_in[2];
    const float* b1  = (const float*)d_in[3];
    const float* Wg  = (const float*)d_in[4];
    const int*   qid = (const int*)d_in[5];
    const int*   did = (const int*)d_in[6];
    float* out = (float*)d_out;

    // workspace (~2.26 MB)
    char* ws = (char*)d_ws;
    unsigned char* g_hist = (unsigned char*)ws;        // 256*16*550 = 2,252,800 B
    float* gate = (float*)(ws + 2252800);              // 1,024 B
    float* ffn  = gate + BATCH;                        // 1,024 B
    int*   cnt  = (int*)(ffn + BATCH);                 // 4 B

    sim_hist_kernel<<<BATCH * SEG, TPB, 0, stream>>>(de, did, qe, qid, Wg,
                                                     g_hist, gate, cnt);
    ffn_score_kernel<<<BATCH, TPB, 0, stream>>>(g_hist, W1, b1, gate, ffn, cnt, out);
}